// Round 2
// baseline (294.987 us; speedup 1.0000x reference)
//
#include <hip/hip_runtime.h>
#include <math.h>

// ReSkipBlockGroup router: fused rms-norm scoring + softmax routing over
// n=6 completed blocks, merged with a partial block.
//
// Shapes: blocks [6, B*T, 1024] fp32, partial [B*T, 1024] fp32,
// w_query/norm_weight [1024] fp32. Output: hidden [B*T,1024] ++ entropy [B*T].
//
// One 256-thread block per token. 1024 floats/row = 256 float4 -> each
// thread owns EXACTLY one float4 per stream; 7 streams = 28 data VGPRs.
// (~70 VGPR total -> 16 waves/CU, 2x the previous wave-per-token layout.)
// All 7 stream loads issued before any dependent compute; one wave
// butterfly (14 values x 6 shfl steps) + 224 B LDS cross-wave reduce;
// softmax merge in closed form (identical math to the verified r0 kernel):
//   hidden = sum_i exp(s_i - M6) * (c1*l/denom) * v_i + (cp/denom) * partial
// Memory-bound: ~268 MB traffic -> ~40 us roofline @ 6.7 TB/s (the rate
// the harness's own fillBuffer dispatches achieve on this box).

#define D 1024
#define NBLK 6

// native vector type — __builtin_nontemporal_* requires this, not HIP_vector_type
typedef float vf4 __attribute__((ext_vector_type(4)));

__global__ __launch_bounds__(256) void reskip_router_kernel(
    const float* __restrict__ blocks,     // [NBLK, BT, D]
    const float* __restrict__ partial,    // [BT, D]
    const float* __restrict__ w_query,    // [D]
    const float* __restrict__ norm_w,     // [D]
    float* __restrict__ out_hidden,       // [BT, D]
    float* __restrict__ out_entropy,      // [BT]
    int BT)
{
    const int tid  = threadIdx.x;         // 0..255: owns float4 #tid of the row
    const int lane = tid & 63;
    const int wv   = tid >> 6;            // wave 0..3
    const int tok  = blockIdx.x;          // one block per token

    const float inv_d     = 1.0f / (float)D;
    const float inv_scale = 1.0f / 32.0f;   // 1/(sqrt(1024)*temperature)
    const float eps       = 1e-6f;

    const size_t tokOff    = (size_t)tok * D;
    const size_t blkStride = (size_t)BT * D;

    // ---- issue ALL bulk loads up front: 7 streams x 1 float4/thread ----
    vf4 v[NBLK + 1];
#pragma unroll
    for (int i = 0; i < NBLK; ++i) {
        const vf4* p = (const vf4*)(blocks + (size_t)i * blkStride + tokOff);
        v[i] = __builtin_nontemporal_load(&p[tid]);
    }
    v[NBLK] = __builtin_nontemporal_load(&((const vf4*)(partial + tokOff))[tid]);

    // effective query chunk (tiny, L2-resident, normal loads)
    vf4 q = ((const vf4*)w_query)[tid] * ((const vf4*)norm_w)[tid];

    // ---- per-thread sumsq + dot for each stream ----
    float ss[NBLK + 1], dt[NBLK + 1];
#pragma unroll
    for (int i = 0; i <= NBLK; ++i) {
        vf4 x = v[i];
        ss[i] = x.x * x.x + x.y * x.y + x.z * x.z + x.w * x.w;
        dt[i] = q.x * x.x + q.y * x.y + q.z * x.z + q.w * x.w;
    }

    // ---- wave butterfly: 14 independent 6-step chains ----
#pragma unroll
    for (int off = 32; off > 0; off >>= 1) {
#pragma unroll
        for (int i = 0; i <= NBLK; ++i) {
            ss[i] += __shfl_xor(ss[i], off, 64);
            dt[i] += __shfl_xor(dt[i], off, 64);
        }
    }

    // ---- cross-wave reduce via 224 B of LDS (broadcast reads: conflict-free) ----
    __shared__ float red[4][2][NBLK + 1];
    if (lane == 0) {
#pragma unroll
        for (int i = 0; i <= NBLK; ++i) {
            red[wv][0][i] = ss[i];
            red[wv][1][i] = dt[i];
        }
    }
    __syncthreads();
#pragma unroll
    for (int i = 0; i <= NBLK; ++i) {
        ss[i] = red[0][0][i] + red[1][0][i] + red[2][0][i] + red[3][0][i];
        dt[i] = red[0][1][i] + red[1][1][i] + red[2][1][i] + red[3][1][i];
    }

    // ---- scores: dot(q, x * rsqrt(mean(x^2)+eps)) / 32 (all threads, redundant) ----
    float sc[NBLK + 1];
#pragma unroll
    for (int i = 0; i <= NBLK; ++i)
        sc[i] = dt[i] * rsqrtf(ss[i] * inv_d + eps) * inv_scale;

    float M6 = sc[0];
#pragma unroll
    for (int i = 1; i < NBLK; ++i) M6 = fmaxf(M6, sc[i]);

    float e[NBLK], l = 0.0f, T = 0.0f;
#pragma unroll
    for (int i = 0; i < NBLK; ++i) {
        float sh = sc[i] - M6;
        e[i] = expf(sh);
        l += e[i];
        T += e[i] * sh;
    }
    float p1_ent = logf(l) - T / l;   // log(L) - (1/L) sum e^sh * sh

    // ---- merge with partial block (closed-form online-softmax merge) ----
    float psc   = sc[NBLK];
    float mm    = fmaxf(M6, psc);
    float c1    = expf(M6 - mm);
    float cp    = expf(psc - mm);
    float denom = c1 * l + cp;
    float w1    = c1 * l / denom;   // phase1_weight
    float wp    = cp / denom;       // partial_weight

    // hidden = routed * w1 + partial * wp, routed = sum_i e_i * v_i (unnormalized)
    vf4 acc = v[NBLK] * wp;
#pragma unroll
    for (int i = 0; i < NBLK; ++i)
        acc += v[i] * (e[i] * w1);
    __builtin_nontemporal_store(acc, &((vf4*)(out_hidden + tokOff))[tid]);

    if (tid == 0) {
        float w1c = fmaxf(w1, 1e-8f);
        float wpc = fmaxf(wp, 1e-8f);
        out_entropy[tok] = w1c * p1_ent - w1c * logf(w1c) - wpc * logf(wpc);
    }
}

extern "C" void kernel_launch(void* const* d_in, const int* in_sizes, int n_in,
                              void* d_out, int out_size, void* d_ws, size_t ws_size,
                              hipStream_t stream) {
    const float* blocks  = (const float*)d_in[0];   // [6, b, t, d]
    const float* partial = (const float*)d_in[1];   // [b, t, d]
    const float* wq      = (const float*)d_in[2];   // [d]
    const float* nw      = (const float*)d_in[3];   // [d]
    float* out = (float*)d_out;

    const int BT = in_sizes[1] / D;                 // b*t
    float* out_hidden  = out;
    float* out_entropy = out + (size_t)BT * D;

    reskip_router_kernel<<<BT, 256, 0, stream>>>(
        blocks, partial, wq, nw, out_hidden, out_entropy, BT);
}

// Round 3
// 285.855 us; speedup vs baseline: 1.0319x; 1.0319x over previous
//
#include <hip/hip_runtime.h>
#include <math.h>

// ReSkipBlockGroup router: fused rms-norm scoring + softmax routing over
// n=6 completed blocks, merged with a partial block.
//
// Shapes: blocks [6, B*T, 1024] fp32, partial [B*T, 1024] fp32,
// w_query/norm_weight [1024] fp32. Output: hidden [B*T,1024] ++ entropy [B*T].
//
// BEST-MEASURED STRUCTURE (restored from round 1, 287.9 us total):
// One 64-lane wave per token; each lane owns 4 coalesced float4 chunks
// (16 floats) of each of the 7 streams -> 112 VGPRs of data held live.
// ALL 28 stream loads are issued before any dependent compute (28 KB in
// flight per wave), then ONE batched 14-value cross-lane butterfly, then
// the two-phase softmax merge in closed form (no online rescale):
//   hidden = sum_i exp(s_i - M6) * (c1*l/denom) * v_i + (cp/denom) * partial
//
// Measurement notes (rocprof r1/r2): timed graph = ~240 us of harness
// re-poison fills (2 x ~120 us @ 83% HBM peak, outside kernel control)
// + this kernel (~48 us vs 43 us stream roofline @ 6.3 TB/s).
// Block-per-token + LDS cross-wave reduce (r2) regressed to ~55 us:
// syncthreads convoy + LDS round-trip on the critical path beat the
// occupancy gain — do not revisit.

#define D 1024
#define NBLK 6
#define C4 4              // float4 chunks per lane: 4 * 64 lanes * 4 floats = 1024

// native vector type — __builtin_nontemporal_* requires this, not HIP_vector_type
typedef float vf4 __attribute__((ext_vector_type(4)));

__global__ __launch_bounds__(256) void reskip_router_kernel(
    const float* __restrict__ blocks,     // [NBLK, BT, D]
    const float* __restrict__ partial,    // [BT, D]
    const float* __restrict__ w_query,    // [D]
    const float* __restrict__ norm_w,     // [D]
    float* __restrict__ out_hidden,       // [BT, D]
    float* __restrict__ out_entropy,      // [BT]
    int BT)
{
    const int wave = threadIdx.x >> 6;
    const int lane = threadIdx.x & 63;
    const int tok  = blockIdx.x * 4 + wave;
    if (tok >= BT) return;

    const float inv_d     = 1.0f / (float)D;
    const float inv_scale = 1.0f / 32.0f;   // 1/(sqrt(1024)*temperature)
    const float eps       = 1e-6f;

    const size_t tokOff    = (size_t)tok * D;
    const size_t blkStride = (size_t)BT * D;

    // ---- issue ALL bulk loads up front: 7 streams x 4 float4/lane ----
    // (all-static indexing; fully unrolled -> stays in VGPRs, no scratch)
    vf4 v[NBLK + 1][C4];
#pragma unroll
    for (int i = 0; i < NBLK; ++i) {
        const vf4* p = (const vf4*)(blocks + (size_t)i * blkStride + tokOff);
#pragma unroll
        for (int c = 0; c < C4; ++c)
            v[i][c] = __builtin_nontemporal_load(&p[c * 64 + lane]);
    }
    {
        const vf4* p = (const vf4*)(partial + tokOff);
#pragma unroll
        for (int c = 0; c < C4; ++c)
            v[NBLK][c] = __builtin_nontemporal_load(&p[c * 64 + lane]);
    }

    // effective query: w_query * norm_weight (tiny, L2-resident, normal loads)
    const vf4* wq4 = (const vf4*)w_query;
    const vf4* nw4 = (const vf4*)norm_w;
    vf4 q[C4];
#pragma unroll
    for (int c = 0; c < C4; ++c)
        q[c] = wq4[c * 64 + lane] * nw4[c * 64 + lane];

    // ---- per-stream lane-local sumsq + dot (compiler pipelines vmcnt) ----
    float ss[NBLK + 1], dt[NBLK + 1];
#pragma unroll
    for (int i = 0; i <= NBLK; ++i) {
        float s = 0.0f, d = 0.0f;
#pragma unroll
        for (int c = 0; c < C4; ++c) {
            vf4 x = v[i][c];
            s += x.x * x.x + x.y * x.y + x.z * x.z + x.w * x.w;
            d += q[c].x * x.x + q[c].y * x.y + q[c].z * x.z + q[c].w * x.w;
        }
        ss[i] = s; dt[i] = d;
    }

    // ---- ONE batched cross-lane reduction: 14 independent 6-step chains ----
#pragma unroll
    for (int off = 32; off > 0; off >>= 1) {
#pragma unroll
        for (int i = 0; i <= NBLK; ++i) {
            ss[i] += __shfl_xor(ss[i], off, 64);
            dt[i] += __shfl_xor(dt[i], off, 64);
        }
    }

    // scores: dot(q, x * rsqrt(mean(x^2)+eps)) / 32
    float sc[NBLK + 1];
#pragma unroll
    for (int i = 0; i <= NBLK; ++i)
        sc[i] = dt[i] * rsqrtf(ss[i] * inv_d + eps) * inv_scale;

    // ---- phase-1 softmax stats over the 6 completed blocks ----
    float M6 = sc[0];
#pragma unroll
    for (int i = 1; i < NBLK; ++i) M6 = fmaxf(M6, sc[i]);

    float e[NBLK], l = 0.0f, T = 0.0f;
#pragma unroll
    for (int i = 0; i < NBLK; ++i) {
        float sh = sc[i] - M6;
        e[i] = expf(sh);
        l += e[i];
        T += e[i] * sh;
    }
    float p1_ent = logf(l) - T / l;   // log(L) - (1/L) sum e^sh * sh

    // ---- merge with partial block (online-softmax merge, closed form) ----
    float psc   = sc[NBLK];
    float mm    = fmaxf(M6, psc);
    float c1    = expf(M6 - mm);
    float cp    = expf(psc - mm);
    float denom = c1 * l + cp;
    float w1    = c1 * l / denom;   // phase1_weight
    float wp    = cp / denom;       // partial_weight

    // hidden = routed * w1 + partial * wp, routed = sum_i e_i * v_i (unnormalized)
    vf4* outp = (vf4*)(out_hidden + tokOff);
#pragma unroll
    for (int c = 0; c < C4; ++c) {
        vf4 acc = v[NBLK][c] * wp;
#pragma unroll
        for (int i = 0; i < NBLK; ++i)
            acc += v[i][c] * (e[i] * w1);
        __builtin_nontemporal_store(acc, &outp[c * 64 + lane]);
    }

    if (lane == 0) {
        float w1c = fmaxf(w1, 1e-8f);
        float wpc = fmaxf(wp, 1e-8f);
        out_entropy[tok] = w1c * p1_ent - w1c * logf(w1c) - wpc * logf(wpc);
    }
}

extern "C" void kernel_launch(void* const* d_in, const int* in_sizes, int n_in,
                              void* d_out, int out_size, void* d_ws, size_t ws_size,
                              hipStream_t stream) {
    const float* blocks  = (const float*)d_in[0];   // [6, b, t, d]
    const float* partial = (const float*)d_in[1];   // [b, t, d]
    const float* wq      = (const float*)d_in[2];   // [d]
    const float* nw      = (const float*)d_in[3];   // [d]
    float* out = (float*)d_out;

    const int BT = in_sizes[1] / D;                 // b*t
    float* out_hidden  = out;
    float* out_entropy = out + (size_t)BT * D;

    const int grid = (BT + 3) / 4;                  // 4 tokens (waves) per block
    reskip_router_kernel<<<grid, 256, 0, stream>>>(
        blocks, partial, wq, nw, out_hidden, out_entropy, BT);
}